// Round 14
// baseline (2752.239 us; speedup 1.0000x reference)
//
#include <hip/hip_runtime.h>

typedef unsigned long long u64;

#define NN 256
#define HD 128
#define GNN_NB 128
#define MLP_NB 64
#define NBLK 192
#define NTHR 512

// ws layout (u64 units): tagged rings, each element = (hi32 tag | lo32 f32 bits)
//   HS ring : [0, 3*32768)       3 slots x 256 rows x 128
//   H1 ring : [98304, +2*32768)
//   flags   : byte offset 1310720: prog 128 lines x 128B, then mf 64 lines x 128B
#define HS_U 0
#define H1_U 98304
#define FLAG_BYTE 1310720

// GNN-block LDS (floats)
#define STH_L 0      // [2][128] own h rows (persist across phases)
#define STM_L 256    // [2][128] combined m rows
#define PT_L  512    // [8][2][128] gather partials
// MLP-block LDS (floats)
#define TGT_L 0
#define PTM_L 2048
#define PT3_L 10240
#define HC_L  11264
#define CT_L  11776
#define CZ_L  12032
#define W2_L  12288
#define HP_L  12544
#define PART_L 12800
#define ANC_L 13312
#define LP_L  13344
#define LDS_FLOATS 13360

// ---- device-coherent access (relaxed agent atomics -> sc1, bypass L1/L2) ----
__device__ __forceinline__ u64 ldp(const u64* p) {
    return __hip_atomic_load(p, __ATOMIC_RELAXED, __HIP_MEMORY_SCOPE_AGENT);
}
__device__ __forceinline__ void stp(u64* p, u64 v) {
    __hip_atomic_store(p, v, __ATOMIC_RELAXED, __HIP_MEMORY_SCOPE_AGENT);
}
__device__ __forceinline__ u64 pk(float v, unsigned tg) {
    return ((u64)tg << 32) | (u64)__float_as_uint(v);
}
#define VALF(v) __uint_as_float((unsigned)(v))
#define TAGU(v) ((unsigned)((v) >> 32))
__device__ __forceinline__ unsigned ldf(const unsigned* p) {
    return __hip_atomic_load(p, __ATOMIC_RELAXED, __HIP_MEMORY_SCOPE_AGENT);
}
__device__ __forceinline__ void stf(unsigned* p, unsigned v) {
    __hip_atomic_store(p, v, __ATOMIC_RELAXED, __HIP_MEMORY_SCOPE_AGENT);
}

// block barrier that does NOT drain vmcnt
__device__ __forceinline__ void bar_lds() {
    asm volatile("s_waitcnt lgkmcnt(0)\n\ts_barrier" ::: "memory");
}

#define ISS(i) \
    u64 va##i, wa##i, vb##i, wb##i, vc##i, wc##i, vd##i, wd##i; \
    if ((i) < nst) { \
        const u64* p_ = gsrc + (i) * 32 * HD; \
        if ((un >> (4*(i)  )) & 1u) { va##i = ldp(p_);          wa##i = ldp(p_ + 1); } \
        if ((un >> (4*(i)+1)) & 1u) { vb##i = ldp(p_ + HD);     wb##i = ldp(p_ + HD + 1); } \
        if ((un >> (4*(i)+2)) & 1u) { vc##i = ldp(p_ + 2*HD);   wc##i = ldp(p_ + 2*HD + 1); } \
        if ((un >> (4*(i)+3)) & 1u) { vd##i = ldp(p_ + 3*HD);   wd##i = ldp(p_ + 3*HD + 1); } \
    }
#define ACCP2(v, w, b) { \
    const float f0_ = (float)((s0 >> (b)) & 1u); \
    const float f1_ = (float)((s1 >> (b)) & 1u); \
    const float x_ = VALF(v), y_ = VALF(w); \
    m0.x = fmaf(f0_, x_, m0.x); m0.y = fmaf(f0_, y_, m0.y); \
    m1.x = fmaf(f1_, x_, m1.x); m1.y = fmaf(f1_, y_, m1.y); }
#define ACC1(v, w, b, po) \
    if ((un >> (b)) & 1u) { \
        while (__builtin_expect(TAGU(v) != etag || TAGU(w) != etag, 0)) { \
            v = ldp(po); w = ldp((po) + 1); } \
        ACCP2(v, w, b) }
#define CNS(i) if ((i) < nst) { \
    ACC1(va##i, wa##i, 4*(i),   gsrc + (i)*32*HD) \
    ACC1(vb##i, wb##i, 4*(i)+1, gsrc + (i)*32*HD + HD) \
    ACC1(vc##i, wc##i, 4*(i)+2, gsrc + (i)*32*HD + 2*HD) \
    ACC1(vd##i, wd##i, 4*(i)+3, gsrc + (i)*32*HD + 3*HD) }

// One GNN layer for rows {R0, R0+1}. Data readiness via per-element tags (etag);
// outputs written tagged with wtag. h rows in STH (LDS); matvec col-per-lane.
__device__ __forceinline__ void layer(const u64* src, u64* dst, unsigned etag, unsigned wtag,
    float bc, const float* z, const float* pos_emb, float* lds,
    const float (&wsA)[32], const float (&wnA)[32],
    unsigned mk0, unsigned mk1,
    int R0, int rmax, int tgate, int tnew, int lane, int wv, int tid, int c, int kbase)
{
    const int rmaxblk = min(rmax, R0 + 1);
    const int nst = (rmaxblk + 31) >> 5;
    const unsigned s0 = (R0     < tgate) ? mk0 : 0u;
    const unsigned s1 = (R0 + 1 < tgate) ? mk1 : 0u;
    const unsigned un = s0 | s1;

    // new node: h row := z + pos_emb[tnew]
    if (tnew >= R0 && tnew < R0 + 2) {
        const int dr = tnew - R0;
        if (tid < HD) lds[STH_L + dr * HD + tid] = z[tid] + pos_emb[tnew * HD + tid];
    }

    // gather: wave wv owns src rows {32c' + 4wv + ss}; tagged loads, poll-on-stale
    const u64* gsrc = src + wv * 4 * HD + 2 * lane;
    float2 m0 = make_float2(0.f, 0.f), m1 = m0;
    ISS(0) ISS(1) ISS(2) ISS(3) ISS(4) ISS(5) ISS(6) ISS(7)
    CNS(0) CNS(1) CNS(2) CNS(3) CNS(4) CNS(5) CNS(6) CNS(7)

    // publish m partials
    float* pt = lds + PT_L + (wv * 2) * HD + 2 * lane;
    *(float2*)pt = m0;
    *(float2*)(pt + HD) = m1;
    bar_lds();
    // combine partials -> STM (2 rows x 128 k, threads 0..255)
    if (tid < 256) {
        const int dr = tid >> 7, k = tid & 127;
        float s = 0.f;
#pragma unroll
        for (int w = 0; w < 8; ++w) s += lds[PT_L + (w * 2 + dr) * HD + k];
        lds[STM_L + dr * HD + k] = s;
    }
    bar_lds();
    // matvec: lane accumulates its col over its 32-k slice, butterfly k-reduce
    float acc0 = 0.f, acc1 = 0.f;
#pragma unroll
    for (int q = 0; q < 8; ++q) {
        const float4 h0 = *(const float4*)(lds + STH_L + kbase + 4 * q);
        const float4 mm0 = *(const float4*)(lds + STM_L + kbase + 4 * q);
        const float4 h1 = *(const float4*)(lds + STH_L + HD + kbase + 4 * q);
        const float4 mm1 = *(const float4*)(lds + STM_L + HD + kbase + 4 * q);
        acc0 = fmaf(h0.x, wsA[4*q],   fmaf(mm0.x, wnA[4*q],   acc0));
        acc0 = fmaf(h0.y, wsA[4*q+1], fmaf(mm0.y, wnA[4*q+1], acc0));
        acc0 = fmaf(h0.z, wsA[4*q+2], fmaf(mm0.z, wnA[4*q+2], acc0));
        acc0 = fmaf(h0.w, wsA[4*q+3], fmaf(mm0.w, wnA[4*q+3], acc0));
        acc1 = fmaf(h1.x, wsA[4*q],   fmaf(mm1.x, wnA[4*q],   acc1));
        acc1 = fmaf(h1.y, wsA[4*q+1], fmaf(mm1.y, wnA[4*q+1], acc1));
        acc1 = fmaf(h1.z, wsA[4*q+2], fmaf(mm1.z, wnA[4*q+2], acc1));
        acc1 = fmaf(h1.w, wsA[4*q+3], fmaf(mm1.w, wnA[4*q+3], acc1));
    }
    acc0 += __shfl_xor(acc0, 16); acc0 += __shfl_xor(acc0, 32);
    acc1 += __shfl_xor(acc1, 16); acc1 += __shfl_xor(acc1, 32);
    const float o0 = fmaxf(acc0 + bc, 0.f);
    const float o1 = fmaxf(acc1 + bc, 0.f);
    const int kg = lane >> 4;
    if (kg == 0) { if (R0     <= rmaxblk) stp(dst + R0 * HD + c, pk(o0, wtag)); }
    else if (kg == 1) { if (R0 + 1 <= rmaxblk) stp(dst + (R0 + 1) * HD + c, pk(o1, wtag)); }
    else if (kg == 2) lds[STH_L + c] = o0;
    else              lds[STH_L + HD + c] = o1;
}

// ---- MLP helpers (tag-polled reads; proven numerics) ----
__device__ __forceinline__ void ct_calc(const u64* hsP, const float* pos_emb,
                                        const float* Wm1, float* lds, int s)
{
    const int tid = threadIdx.x;
    if (tid < 64) {
        const u64* p = hsP + s * HD + 2 * tid;
        u64 a = ldp(p), b2 = ldp(p + 1);
        const unsigned e = (unsigned)s;
        while (__builtin_expect(TAGU(a) != e || TAGU(b2) != e, 0)) { a = ldp(p); b2 = ldp(p + 1); }
        lds[HP_L + 2 * tid] = VALF(a); lds[HP_L + 2 * tid + 1] = VALF(b2);
    } else if (tid < 128) {
        const int l2 = tid - 64;
        lds[HP_L + 128 + 2 * l2]     = pos_emb[s * HD + 2 * l2];
        lds[HP_L + 128 + 2 * l2 + 1] = pos_emb[s * HD + 2 * l2 + 1];
    }
    __syncthreads();
    const int c = tid & 255, half = tid >> 8;
    float acc = 0.f;
    const float* w = half ? (Wm1 + 384 * 256 + c) : (Wm1 + c);
    const float* hh = lds + HP_L + half * 128;
#pragma unroll 4
    for (int k = 0; k < HD; ++k) acc = fmaf(hh[k], w[k * 256], acc);
    lds[PART_L + half * 256 + c] = acc;
    __syncthreads();
    if (tid < 256)
        lds[CT_L + tid] = lds[CZ_L + tid] + lds[PART_L + tid] + lds[PART_L + 256 + tid];
}

__device__ __forceinline__ void mlp_step(const u64* hsP, const float* bm2,
                                         const float4 (&wm)[16], float* lds, int mb, int s)
{
    const int tid = threadIdx.x, lane = tid & 63, wv = tid >> 6;
    const int ks = wv * 16;
    if (wv < 4) {
        const int i = 4 * mb + wv;
        float vx = 0.f, vy = 0.f;
        if (i < s) {
            const u64* p = hsP + i * HD + 2 * lane;
            u64 a = ldp(p), b2 = ldp(p + 1);
            const unsigned e = (unsigned)s;
            while (__builtin_expect(TAGU(a) != e || TAGU(b2) != e, 0)) { a = ldp(p); b2 = ldp(p + 1); }
            vx = VALF(a); vy = VALF(b2);
        }
        lds[HC_L + wv * HD + 2 * lane] = vx;
        lds[HC_L + wv * HD + 2 * lane + 1] = vy;
    }
    __syncthreads();
    float4 a0 = make_float4(0.f, 0.f, 0.f, 0.f), a1 = a0, a2 = a0, a3 = a0;
#pragma unroll
    for (int kk = 0; kk < 16; ++kk) {
        const int k = ks + kk;
        const float h0 = lds[HC_L + 0 * HD + k];
        const float h1 = lds[HC_L + 1 * HD + k];
        const float h2 = lds[HC_L + 2 * HD + k];
        const float h3 = lds[HC_L + 3 * HD + k];
        const float4 w = wm[kk];
        a0.x = fmaf(h0, w.x, a0.x); a0.y = fmaf(h0, w.y, a0.y);
        a0.z = fmaf(h0, w.z, a0.z); a0.w = fmaf(h0, w.w, a0.w);
        a1.x = fmaf(h1, w.x, a1.x); a1.y = fmaf(h1, w.y, a1.y);
        a1.z = fmaf(h1, w.z, a1.z); a1.w = fmaf(h1, w.w, a1.w);
        a2.x = fmaf(h2, w.x, a2.x); a2.y = fmaf(h2, w.y, a2.y);
        a2.z = fmaf(h2, w.z, a2.z); a2.w = fmaf(h2, w.w, a2.w);
        a3.x = fmaf(h3, w.x, a3.x); a3.y = fmaf(h3, w.y, a3.y);
        a3.z = fmaf(h3, w.z, a3.z); a3.w = fmaf(h3, w.w, a3.w);
    }
    *(float4*)(lds + PTM_L + (wv * 4 + 0) * 256 + 4 * lane) = a0;
    *(float4*)(lds + PTM_L + (wv * 4 + 1) * 256 + 4 * lane) = a1;
    *(float4*)(lds + PTM_L + (wv * 4 + 2) * 256 + 4 * lane) = a2;
    *(float4*)(lds + PTM_L + (wv * 4 + 3) * 256 + 4 * lane) = a3;
    __syncthreads();
    {
        const int c = tid & 255, ci2 = (tid >> 8) * 2;
#pragma unroll
        for (int q = 0; q < 2; ++q) {
            const int ci = ci2 + q;
            float v = lds[CT_L + c];
#pragma unroll
            for (int w = 0; w < 8; ++w) v += lds[PTM_L + (w * 4 + ci) * 256 + c];
            lds[PT3_L + ci * 256 + c] = fmaxf(v, 0.f) * lds[W2_L + c];
        }
    }
    __syncthreads();
    if (wv < 4) {
        const int ci = wv, i = 4 * mb + ci;
        if (i < s) {
            float sd = lds[PT3_L + ci * 256 + lane] + lds[PT3_L + ci * 256 + 64 + lane]
                     + lds[PT3_L + ci * 256 + 128 + lane] + lds[PT3_L + ci * 256 + 192 + lane];
#pragma unroll
            for (int off = 32; off > 0; off >>= 1) sd += __shfl_xor(sd, off);
            if (lane == 0) {
                const unsigned* gtl = (const unsigned*)(lds + TGT_L) + s * 8;
                unsigned* ancl = (unsigned*)(lds + ANC_L);
                const float logit = sd + bm2[0];
                const float prob = 1.f / (1.f + expf(-logit));
                unsigned cnt = 0, has = 0;
#pragma unroll
                for (int w = 0; w < 8; ++w) {
                    const unsigned av = ancl[ci * 8 + w];
                    cnt += __popc(av);
                    has |= av & gtl[w];
                }
                const float supp = ldexpf(1.f, -(int)cnt);  // 0.5^cnt exact
                const float adj = prob * supp;
                const unsigned gt = (gtl[i >> 5] >> (i & 31)) & 1u;
                const float lpv = gt ? logf(adj + 1e-12f) : logf(1.f - adj + 1e-12f);
                atomicAdd((float*)(lds + LP_L), lpv);
                if (has | gt) ancl[ci * 8 + (s >> 5)] |= (1u << (s & 31));
            }
        }
    }
}

extern "C" __global__ void __launch_bounds__(NTHR)
fused_gnn(const float* z, const int* targets, const float* pos_emb,
          const float* Ws1, const float* Wn1, const float* b1,
          const float* Ws2, const float* Wn2, const float* b2,
          const float* Wm1, const float* bm1, const float* Wm2, const float* bm2,
          const float* Wf, const float* bf, float* out, float* ws)
{
    __shared__ __align__(16) float lds[LDS_FLOATS];
    const int b = blockIdx.x;
    const int tid = threadIdx.x, lane = tid & 63, wv = tid >> 6;

    u64* wsu = (u64*)ws;
    u64* hsRing = wsu + HS_U;
    u64* h1Ring = wsu + H1_U;
    unsigned* prog = (unsigned*)((char*)ws + FLAG_BYTE);
    unsigned* mf = prog + 128 * 32;
    float* lp_out = out + NN * NN + NN * 16;

    if (b < GNN_NB) {
        const int R0 = b * 2;
        const int c = 16 * wv + (lane & 15);
        const int kbase = 32 * (lane >> 4);
        float ws1[32], wn1[32], ws2[32], wn2[32];
#pragma unroll
        for (int i = 0; i < 32; ++i) {
            ws1[i] = Ws1[(kbase + i) * HD + c];
            wn1[i] = Wn1[(kbase + i) * HD + c];
            ws2[i] = Ws2[(kbase + i) * HD + c];
            wn2[i] = Wn2[(kbase + i) * HD + c];
        }
        const float b1c = b1[c], b2c = b2[c];
        unsigned mk0, mk1;
        {
            const int srcl = (lane < 32) ? (((lane >> 2) << 5) + wv * 4 + (lane & 3)) : 0;
#define BALLOT_MK(dr, dst) { \
            const int r_ = R0 + (dr); \
            const bool p_ = (lane < 32) && (srcl < r_) && (targets[r_ * NN + srcl] != 0); \
            const unsigned long long bm_ = __ballot(p_); \
            dst = (unsigned)__builtin_amdgcn_readfirstlane((int)(unsigned)bm_); }
            BALLOT_MK(0, mk0) BALLOT_MK(1, mk1)
#undef BALLOT_MK
        }
        // init: STH, Hs(0) slot 0 (tagged 0), tgt output
        if (tid < 256) lds[STH_L + tid] = (b == 0 && tid < HD) ? z[tid] : 0.f;
        if (tid < 256) {
            const int dr = tid >> 7, cc = tid & 127, r = R0 + dr;
            stp(hsRing + r * HD + cc, pk((r == 0) ? z[cc] : 0.f, 0u));
        }
        if (wv < 2) {
            const int r = R0 + wv;
            const int4 tv = ((const int4*)(targets + r * NN))[lane];
            float4 ov;
            ov.x = (4 * lane     < r) ? (float)tv.x : 0.f;
            ov.y = (4 * lane + 1 < r) ? (float)tv.y : 0.f;
            ov.z = (4 * lane + 2 < r) ? (float)tv.z : 0.f;
            ov.w = (4 * lane + 3 < r) ? (float)tv.w : 0.f;
            ((float4*)(out + r * NN))[lane] = ov;
        }
        __syncthreads();  // drain init stores
        if (tid == 0) stf(prog + b * 32, 1u);

        unsigned seenP = 0;
        int      seenM = 0;

        for (int t = 1; t <= 256; ++t) {
            const u64* hsP = hsRing + ((t - 1) % 3) * 32768;
            u64* h1c = h1Ring + (t & 1) * 32768;
            u64* hsN = hsRing + (t % 3) * 32768;
            const int rmax  = (t <= 255) ? t : 255;
            const int tgate = (t <= 255) ? t : 300;
            const int tnew  = (t <= 255) ? t : -1;
            const bool act = (R0 <= rmax);

            // layer1(t): data via tags; ring wait only (H1 slot occupant t-2)
            if (act) {
                if (t > 2 && tid < GNN_NB) {
                    const unsigned th = 2u * (t - 2) + 1u;
                    if (seenP < th) {
                        unsigned v;
                        for (;;) {
                            v = ldf(prog + tid * 32);
                            if (v >= th) break;
                            __builtin_amdgcn_s_sleep(1);
                        }
                        seenP = v;
                    }
                }
                __syncthreads();
                asm volatile("" ::: "memory");
                layer(hsP, h1c, (unsigned)(t - 1), (unsigned)t, b1c, z, pos_emb, lds,
                      ws1, wn1, mk0, mk1, R0, rmax, tgate, tnew, lane, wv, tid, c, kbase);
            }
            __syncthreads();
            if (tid == 0) stf(prog + b * 32, 2u * t);

            // layer2(t): data via tags; ring wait (Hs slot occupant t-3) + sparse mf
            if (act) {
                {
                    const unsigned ringTh = (t > 3) ? (2u * (t - 2)) : 0u;
                    const int mlpTh = t - 3;
                    const bool ownRow = (mlpTh > 0) && ((mlpTh >> 1) == b);
                    if (tid < GNN_NB) {
                        if (ringTh && seenP < ringTh) {
                            unsigned v;
                            for (;;) {
                                v = ldf(prog + tid * 32);
                                if (v >= ringTh) break;
                                __builtin_amdgcn_s_sleep(1);
                            }
                            seenP = v;
                        }
                    } else if (tid < GNN_NB + MLP_NB) {
                        const int mi = tid - GNN_NB;
                        const int thm = (mlpTh > 0 && (mi == (b >> 1) || ownRow)) ? mlpTh : 0;
                        if (thm > 0 && seenM < thm) {
                            int v;
                            for (;;) {
                                v = (int)ldf(mf + mi * 32);
                                if (v >= thm) break;
                                __builtin_amdgcn_s_sleep(1);
                            }
                            seenM = v;
                        }
                    }
                    __syncthreads();
                    asm volatile("" ::: "memory");
                }
                layer(h1c, hsN, (unsigned)t, (unsigned)t, b2c, z, pos_emb, lds,
                      ws2, wn2, mk0, mk1, R0, rmax, tgate, -1, lane, wv, tid, c, kbase);
            }
            __syncthreads();
            if (tid == 0) stf(prog + b * 32, 2u * t + 1u);
        }

        // X_out from STH (final Hs rows of this block)
        if (wv < 2) {
            const int r = R0 + wv;
            const float* strow = lds + STH_L + wv * HD;
            const int f = lane & 15, kp = lane >> 4;
            float sacc = 0.f;
#pragma unroll
            for (int k = 0; k < 32; ++k)
                sacc = fmaf(strow[kp * 32 + k], Wf[(kp * 32 + k) * 16 + f], sacc);
            sacc += __shfl_xor(sacc, 16);
            sacc += __shfl_xor(sacc, 32);
            if (lane < 16) out[NN * NN + r * 16 + f] = sacc + bf[f];
        }
    } else {
        // ---- MLP block: data readiness purely via tags; posts mf for ring guard ----
        const int mb = b - GNN_NB;
        const int ks = wv * 16;
        float4 wm[16];
#pragma unroll
        for (int kk = 0; kk < 16; ++kk)
            wm[kk] = *(const float4*)(Wm1 + (128 + ks + kk) * 256 + 4 * lane);
        {
            unsigned* tg = (unsigned*)(lds + TGT_L);
            for (int rr = 0; rr < 32; ++rr) {
                const int r = wv * 32 + rr;
#pragma unroll
                for (int q = 0; q < 4; ++q) {
                    const int j = q * 64 + lane;
                    const unsigned long long bm = __ballot(j < r && targets[r * NN + j] != 0);
                    if (lane == 0) {
                        tg[r * 8 + 2 * q]     = (unsigned)bm;
                        tg[r * 8 + 2 * q + 1] = (unsigned)(bm >> 32);
                    }
                }
            }
        }
        if (tid < 256) {
            lds[W2_L + tid] = Wm2[tid];
            float acc = bm1[tid];
            for (int k = 0; k < HD; ++k) acc = fmaf(z[k], Wm1[(256 + k) * 256 + tid], acc);
            lds[CZ_L + tid] = acc;
        }
        if (tid < 32) ((unsigned*)(lds + ANC_L))[tid] = 0u;
        if (tid == 0) lds[LP_L] = 0.f;
        __syncthreads();

        for (int s = 1; s <= 255; ++s) {
            const u64* hsP = hsRing + (s % 3) * 32768;
            if (4 * mb < s) {
                ct_calc(hsP, pos_emb, Wm1, lds, s);
                __syncthreads();
                mlp_step(hsP, bm2, wm, lds, mb, s);
            }
            __syncthreads();  // all reads of Hs(s) done (vmcnt drained per wave)
            if (tid == 0) stf(mf + mb * 32, (unsigned)s);
        }
        __syncthreads();
        if (tid == 0) atomicAdd(lp_out, lds[LP_L]);
    }
}

extern "C" void kernel_launch(void* const* d_in, const int* in_sizes, int n_in,
                              void* d_out, int out_size, void* d_ws, size_t ws_size,
                              hipStream_t stream)
{
    const float* z       = (const float*)d_in[0];
    const int*   targets = (const int*)d_in[1];
    const float* pos_emb = (const float*)d_in[2];
    const float* Ws1     = (const float*)d_in[3];
    const float* Wn1     = (const float*)d_in[4];
    const float* b1      = (const float*)d_in[5];
    const float* Ws2     = (const float*)d_in[6];
    const float* Wn2     = (const float*)d_in[7];
    const float* b2      = (const float*)d_in[8];
    const float* Wm1     = (const float*)d_in[9];
    const float* bm1     = (const float*)d_in[10];
    const float* Wm2     = (const float*)d_in[11];
    const float* bm2     = (const float*)d_in[12];
    const float* Wf      = (const float*)d_in[13];
    const float* bf      = (const float*)d_in[14];
    float* out = (float*)d_out;
    float* ws  = (float*)d_ws;

    // zero prog + mf flag lines and the lp accumulator each call
    (void)hipMemsetAsync((char*)d_ws + FLAG_BYTE, 0, (128 + 64) * 32 * sizeof(unsigned), stream);
    (void)hipMemsetAsync(out + NN * NN + NN * 16, 0, sizeof(float), stream);

    void* args[17] = {
        (void*)&z, (void*)&targets, (void*)&pos_emb,
        (void*)&Ws1, (void*)&Wn1, (void*)&b1,
        (void*)&Ws2, (void*)&Wn2, (void*)&b2,
        (void*)&Wm1, (void*)&bm1, (void*)&Wm2, (void*)&bm2,
        (void*)&Wf, (void*)&bf, (void*)&out, (void*)&ws
    };
    (void)hipLaunchCooperativeKernel((const void*)fused_gnn, dim3(NBLK), dim3(NTHR),
                                     args, 0, stream);
}

// Round 15
// 2275.399 us; speedup vs baseline: 1.2096x; 1.2096x over previous
//
#include <hip/hip_runtime.h>

#define NN 256
#define HD 128
#define GNN_NB 128
#define MLP_NB 64
#define NBLK 192
#define NTHR 512

// ws float offsets (cross-block-mutable data accessed ONLY via sc1 atomics)
#define HS_OFF 0                   // ring: 3 x 32768 floats
#define H1R_OFF 98304              // ring: 2 x 32768 floats
#define PROG8_OFF 163840           // 128 blk x 8 waves flags, stride 32 u32
#define MF_OFF (163840 + 32768)    // 64 mlp flags, stride 32 u32

// GNN-block LDS (floats)
#define STH_L 0      // [2 parity][2 rows][128] own h rows
#define STM_L 512    // [2][128] combined m rows
#define PT_L  768    // [8][2][128] gather partials
// MLP-block LDS (floats)
#define TGT_L 0
#define PTM_L 2048
#define PT3_L 10240
#define HC_L  11264
#define CT_L  11776
#define CZ_L  12032
#define W2_L  12288
#define HP_L  12544
#define PART_L 12800
#define ANC_L 13312
#define LP_L  13344
#define LDS_FLOATS 13360

// ---- device-coherent access (relaxed agent atomics -> sc1, bypass L1/L2) ----
__device__ __forceinline__ float2 ldc_f2(const float* p) {
    unsigned long long u = __hip_atomic_load((const unsigned long long*)p,
                                             __ATOMIC_RELAXED, __HIP_MEMORY_SCOPE_AGENT);
    float2 r;
    r.x = __uint_as_float((unsigned)u);
    r.y = __uint_as_float((unsigned)(u >> 32));
    return r;
}
__device__ __forceinline__ void stc_f(float* p, float v) {
    __hip_atomic_store((unsigned*)p, __float_as_uint(v),
                       __ATOMIC_RELAXED, __HIP_MEMORY_SCOPE_AGENT);
}
__device__ __forceinline__ unsigned ldf(const unsigned* p) {
    return __hip_atomic_load(p, __ATOMIC_RELAXED, __HIP_MEMORY_SCOPE_AGENT);
}
__device__ __forceinline__ void stf(unsigned* p, unsigned v) {
    __hip_atomic_store(p, v, __ATOMIC_RELAXED, __HIP_MEMORY_SCOPE_AGENT);
}

// block barrier that does NOT drain vmcnt
__device__ __forceinline__ void bar_lds() {
    asm volatile("s_waitcnt lgkmcnt(0)\n\ts_barrier" ::: "memory");
}

#define POLLW(ptr, th, cache) \
    if ((cache) < (th)) { \
        unsigned v_; \
        for (;;) { v_ = ldf(ptr); if (v_ >= (th)) break; __builtin_amdgcn_s_sleep(1); } \
        (cache) = v_; \
    }

#define ISS(i) \
    float2 va##i, vb##i, vc##i, vd##i; \
    if ((i) < nst) { \
        const float* p_ = gsrc + (i) * 32 * HD; \
        if ((un >> (4 * (i)    )) & 1u) va##i = ldc_f2(p_); \
        if ((un >> (4 * (i) + 1)) & 1u) vb##i = ldc_f2(p_ + HD); \
        if ((un >> (4 * (i) + 2)) & 1u) vc##i = ldc_f2(p_ + 2 * HD); \
        if ((un >> (4 * (i) + 3)) & 1u) vd##i = ldc_f2(p_ + 3 * HD); \
    }
#define ACCP(v, b) { \
    const float f0_ = (float)((s0 >> (b)) & 1u); \
    const float f1_ = (float)((s1 >> (b)) & 1u); \
    m0.x = fmaf(f0_, v.x, m0.x); m0.y = fmaf(f0_, v.y, m0.y); \
    m1.x = fmaf(f1_, v.x, m1.x); m1.y = fmaf(f1_, v.y, m1.y); }
#define ACC1(v, b) if ((un >> (b)) & 1u) { ACCP(v, b) }
#define CNS(i) if ((i) < nst) { ACC1(va##i, 4*(i)) ACC1(vb##i, 4*(i)+1) \
                                ACC1(vc##i, 4*(i)+2) ACC1(vd##i, 4*(i)+3) }

// One GNN layer for rows {R0, R0+1}. h rows in STH[pr] (LDS), outputs h -> STH[pr^1].
// Gather sc1 direct-to-register; matvec col-per-lane with shuffle k-reduce.
__device__ __forceinline__ void layer(const float* src, float* dst, float bc,
    const float* z, const float* pos_emb, float* lds,
    const float (&wsA)[32], const float (&wnA)[32],
    unsigned mk0, unsigned mk1,
    int R0, int rmax, int tgate, int tnew, int lane, int wv, int tid, int c, int kbase,
    int pr)
{
    const int rmaxblk = min(rmax, R0 + 1);
    const int nst = (rmaxblk + 31) >> 5;
    const unsigned s0 = (R0     < tgate) ? mk0 : 0u;
    const unsigned s1 = (R0 + 1 < tgate) ? mk1 : 0u;
    const unsigned un = s0 | s1;
    float* sthR = lds + STH_L + pr * 256;        // read buffer
    float* sthW = lds + STH_L + (pr ^ 1) * 256;  // write buffer

    // new node: h row := z + pos_emb[tnew] (into READ buffer, used this phase)
    if (tnew >= R0 && tnew < R0 + 2) {
        const int dr = tnew - R0;
        if (tid < HD) sthR[dr * HD + tid] = z[tid] + pos_emb[tnew * HD + tid];
    }

    // gather: wave wv owns src rows {32c' + 4wv + ss}; masked loads all in flight
    const float* gsrc = src + wv * 4 * HD + 2 * lane;
    float2 m0 = make_float2(0.f, 0.f), m1 = m0;
    ISS(0) ISS(1) ISS(2) ISS(3) ISS(4) ISS(5) ISS(6) ISS(7)
    CNS(0) CNS(1) CNS(2) CNS(3) CNS(4) CNS(5) CNS(6) CNS(7)

    // publish m partials
    float* pt = lds + PT_L + (wv * 2) * HD + 2 * lane;
    *(float2*)pt = m0;
    *(float2*)(pt + HD) = m1;
    bar_lds();
    // combine partials -> STM (2 rows x 128 k, threads 0..255)
    if (tid < 256) {
        const int dr = tid >> 7, k = tid & 127;
        float s = 0.f;
#pragma unroll
        for (int w = 0; w < 8; ++w) s += lds[PT_L + (w * 2 + dr) * HD + k];
        lds[STM_L + dr * HD + k] = s;
    }
    bar_lds();
    // matvec: lane accumulates its col over its 32-k slice, butterfly k-reduce
    float acc0 = 0.f, acc1 = 0.f;
#pragma unroll
    for (int q = 0; q < 8; ++q) {
        const float4 h0 = *(const float4*)(sthR + kbase + 4 * q);
        const float4 mm0 = *(const float4*)(lds + STM_L + kbase + 4 * q);
        const float4 h1 = *(const float4*)(sthR + HD + kbase + 4 * q);
        const float4 mm1 = *(const float4*)(lds + STM_L + HD + kbase + 4 * q);
        acc0 = fmaf(h0.x, wsA[4*q],   fmaf(mm0.x, wnA[4*q],   acc0));
        acc0 = fmaf(h0.y, wsA[4*q+1], fmaf(mm0.y, wnA[4*q+1], acc0));
        acc0 = fmaf(h0.z, wsA[4*q+2], fmaf(mm0.z, wnA[4*q+2], acc0));
        acc0 = fmaf(h0.w, wsA[4*q+3], fmaf(mm0.w, wnA[4*q+3], acc0));
        acc1 = fmaf(h1.x, wsA[4*q],   fmaf(mm1.x, wnA[4*q],   acc1));
        acc1 = fmaf(h1.y, wsA[4*q+1], fmaf(mm1.y, wnA[4*q+1], acc1));
        acc1 = fmaf(h1.z, wsA[4*q+2], fmaf(mm1.z, wnA[4*q+2], acc1));
        acc1 = fmaf(h1.w, wsA[4*q+3], fmaf(mm1.w, wnA[4*q+3], acc1));
    }
    acc0 += __shfl_xor(acc0, 16); acc0 += __shfl_xor(acc0, 32);
    acc1 += __shfl_xor(acc1, 16); acc1 += __shfl_xor(acc1, 32);
    const float o0 = fmaxf(acc0 + bc, 0.f);
    const float o1 = fmaxf(acc1 + bc, 0.f);
    // store + next-phase STH (parity write buffer: no cross-wave race)
    const int kg = lane >> 4;
    if (kg == 0) { if (R0     <= rmaxblk) stc_f(dst + R0 * HD + c, o0); }
    else if (kg == 1) { if (R0 + 1 <= rmaxblk) stc_f(dst + (R0 + 1) * HD + c, o1); }
    else if (kg == 2) sthW[c] = o0;
    else              sthW[HD + c] = o1;
}

// ---- MLP helpers (proven numerics) ----
__device__ __forceinline__ void ct_calc(const float* hsP, const float* pos_emb,
                                        const float* Wm1, float* lds, int s)
{
    const int tid = threadIdx.x;
    if (tid < 64) {
        const float2 v = ldc_f2(hsP + s * HD + 2 * tid);
        lds[HP_L + 2 * tid] = v.x; lds[HP_L + 2 * tid + 1] = v.y;
    } else if (tid < 128) {
        const int l2 = tid - 64;
        lds[HP_L + 128 + 2 * l2]     = pos_emb[s * HD + 2 * l2];
        lds[HP_L + 128 + 2 * l2 + 1] = pos_emb[s * HD + 2 * l2 + 1];
    }
    __syncthreads();
    const int c = tid & 255, half = tid >> 8;
    float acc = 0.f;
    const float* w = half ? (Wm1 + 384 * 256 + c) : (Wm1 + c);
    const float* hh = lds + HP_L + half * 128;
#pragma unroll 4
    for (int k = 0; k < HD; ++k) acc = fmaf(hh[k], w[k * 256], acc);
    lds[PART_L + half * 256 + c] = acc;
    __syncthreads();
    if (tid < 256)
        lds[CT_L + tid] = lds[CZ_L + tid] + lds[PART_L + tid] + lds[PART_L + 256 + tid];
}

__device__ __forceinline__ void mlp_step(const float* hsP, const float* bm2,
                                         const float4 (&wm)[16], float* lds, int mb, int s)
{
    const int tid = threadIdx.x, lane = tid & 63, wv = tid >> 6;
    const int ks = wv * 16;
    if (wv < 4) {
        const int i = 4 * mb + wv;
        float2 v = make_float2(0.f, 0.f);
        if (i < s) v = ldc_f2(hsP + i * HD + 2 * lane);
        *(float2*)(lds + HC_L + wv * HD + 2 * lane) = v;
    }
    __syncthreads();
    float4 a0 = make_float4(0.f, 0.f, 0.f, 0.f), a1 = a0, a2 = a0, a3 = a0;
#pragma unroll
    for (int kk = 0; kk < 16; ++kk) {
        const int k = ks + kk;
        const float h0 = lds[HC_L + 0 * HD + k];
        const float h1 = lds[HC_L + 1 * HD + k];
        const float h2 = lds[HC_L + 2 * HD + k];
        const float h3 = lds[HC_L + 3 * HD + k];
        const float4 w = wm[kk];
        a0.x = fmaf(h0, w.x, a0.x); a0.y = fmaf(h0, w.y, a0.y);
        a0.z = fmaf(h0, w.z, a0.z); a0.w = fmaf(h0, w.w, a0.w);
        a1.x = fmaf(h1, w.x, a1.x); a1.y = fmaf(h1, w.y, a1.y);
        a1.z = fmaf(h1, w.z, a1.z); a1.w = fmaf(h1, w.w, a1.w);
        a2.x = fmaf(h2, w.x, a2.x); a2.y = fmaf(h2, w.y, a2.y);
        a2.z = fmaf(h2, w.z, a2.z); a2.w = fmaf(h2, w.w, a2.w);
        a3.x = fmaf(h3, w.x, a3.x); a3.y = fmaf(h3, w.y, a3.y);
        a3.z = fmaf(h3, w.z, a3.z); a3.w = fmaf(h3, w.w, a3.w);
    }
    *(float4*)(lds + PTM_L + (wv * 4 + 0) * 256 + 4 * lane) = a0;
    *(float4*)(lds + PTM_L + (wv * 4 + 1) * 256 + 4 * lane) = a1;
    *(float4*)(lds + PTM_L + (wv * 4 + 2) * 256 + 4 * lane) = a2;
    *(float4*)(lds + PTM_L + (wv * 4 + 3) * 256 + 4 * lane) = a3;
    __syncthreads();
    {
        const int c = tid & 255, ci2 = (tid >> 8) * 2;
#pragma unroll
        for (int q = 0; q < 2; ++q) {
            const int ci = ci2 + q;
            float v = lds[CT_L + c];
#pragma unroll
            for (int w = 0; w < 8; ++w) v += lds[PTM_L + (w * 4 + ci) * 256 + c];
            lds[PT3_L + ci * 256 + c] = fmaxf(v, 0.f) * lds[W2_L + c];
        }
    }
    __syncthreads();
    if (wv < 4) {
        const int ci = wv, i = 4 * mb + ci;
        if (i < s) {
            float sd = lds[PT3_L + ci * 256 + lane] + lds[PT3_L + ci * 256 + 64 + lane]
                     + lds[PT3_L + ci * 256 + 128 + lane] + lds[PT3_L + ci * 256 + 192 + lane];
#pragma unroll
            for (int off = 32; off > 0; off >>= 1) sd += __shfl_xor(sd, off);
            if (lane == 0) {
                const unsigned* gtl = (const unsigned*)(lds + TGT_L) + s * 8;
                unsigned* ancl = (unsigned*)(lds + ANC_L);
                const float logit = sd + bm2[0];
                const float prob = 1.f / (1.f + expf(-logit));
                unsigned cnt = 0, has = 0;
#pragma unroll
                for (int w = 0; w < 8; ++w) {
                    const unsigned av = ancl[ci * 8 + w];
                    cnt += __popc(av);
                    has |= av & gtl[w];
                }
                const float supp = ldexpf(1.f, -(int)cnt);  // 0.5^cnt exact
                const float adj = prob * supp;
                const unsigned gt = (gtl[i >> 5] >> (i & 31)) & 1u;
                const float lpv = gt ? logf(adj + 1e-12f) : logf(1.f - adj + 1e-12f);
                atomicAdd((float*)(lds + LP_L), lpv);
                if (has | gt) ancl[ci * 8 + (s >> 5)] |= (1u << (s & 31));
            }
        }
    }
}

extern "C" __global__ void __launch_bounds__(NTHR)
fused_gnn(const float* z, const int* targets, const float* pos_emb,
          const float* Ws1, const float* Wn1, const float* b1,
          const float* Ws2, const float* Wn2, const float* b2,
          const float* Wm1, const float* bm1, const float* Wm2, const float* bm2,
          const float* Wf, const float* bf, float* out, float* ws)
{
    __shared__ __align__(16) float lds[LDS_FLOATS];
    const int b = blockIdx.x;
    const int tid = threadIdx.x, lane = tid & 63, wv = tid >> 6;

    unsigned* prog8 = (unsigned*)(ws + PROG8_OFF);  // [128 blk][8 wave] lines
    unsigned* mf    = (unsigned*)(ws + MF_OFF);
    float* lp_out = out + NN * NN + NN * 16;

    if (b < GNN_NB) {
        const int R0 = b * 2;
        const int c = 16 * wv + (lane & 15);
        const int kbase = 32 * (lane >> 4);
        float ws1[32], wn1[32], ws2[32], wn2[32];
#pragma unroll
        for (int i = 0; i < 32; ++i) {
            ws1[i] = Ws1[(kbase + i) * HD + c];
            wn1[i] = Wn1[(kbase + i) * HD + c];
            ws2[i] = Ws2[(kbase + i) * HD + c];
            wn2[i] = Wn2[(kbase + i) * HD + c];
        }
        const float b1c = b1[c], b2c = b2[c];
        unsigned mk0, mk1;
        {
            const int srcl = (lane < 32) ? (((lane >> 2) << 5) + wv * 4 + (lane & 3)) : 0;
#define BALLOT_MK(dr, dst) { \
            const int r_ = R0 + (dr); \
            const bool p_ = (lane < 32) && (srcl < r_) && (targets[r_ * NN + srcl] != 0); \
            const unsigned long long bm_ = __ballot(p_); \
            dst = (unsigned)__builtin_amdgcn_readfirstlane((int)(unsigned)bm_); }
            BALLOT_MK(0, mk0) BALLOT_MK(1, mk1)
#undef BALLOT_MK
        }
        // init: STH parity0, Hs(0) slot 0, tgt output
        if (tid < 256) lds[STH_L + tid] = (b == 0 && tid < HD) ? z[tid] : 0.f;
        if (tid < 256) {
            const int dr = tid >> 7, cc = tid & 127, r = R0 + dr;
            stc_f(ws + HS_OFF + r * HD + cc, (r == 0) ? z[cc] : 0.f);
        }
        if (wv < 2) {
            const int r = R0 + wv;
            const int4 tv = ((const int4*)(targets + r * NN))[lane];
            float4 ov;
            ov.x = (4 * lane     < r) ? (float)tv.x : 0.f;
            ov.y = (4 * lane + 1 < r) ? (float)tv.y : 0.f;
            ov.z = (4 * lane + 2 < r) ? (float)tv.z : 0.f;
            ov.w = (4 * lane + 3 < r) ? (float)tv.w : 0.f;
            ((float4*)(out + r * NN))[lane] = ov;
        }
        // per-wave drain + sub-flag post (init = 1)
        asm volatile("s_waitcnt vmcnt(0)" ::: "memory");
        if (lane == 0) stf(prog8 + (b * 8 + wv) * 32, 1u);

        // poll assignment: thread tid -> flag tid (block tid>>3) and flag tid+512
        const int bA = tid >> 3, bB = 64 + (tid >> 3);
        unsigned sA = 0, sB = 0;   // monotone caches
        int      sM = 0;           // mf cache (tid < 64)

        // prologue poll: layer1(1) data deps (blk < b >= 1)
        {
            if (bA < b) POLLW(prog8 + tid * 32, 1u, sA)
            if (bB < b) POLLW(prog8 + (tid + 512) * 32, 1u, sB)
        }
        asm volatile("" ::: "memory");
        __syncthreads();

        for (int t = 1; t <= 256; ++t) {
            const float* hsP = ws + HS_OFF + ((t - 1) % 3) * 32768;
            float* h1c = ws + H1R_OFF + (t & 1) * 32768;
            float* hsN = ws + HS_OFF + (t % 3) * 32768;
            const int rmax  = (t <= 255) ? t : 255;
            const int tgate = (t <= 255) ? t : 300;
            const int tnew  = (t <= 255) ? t : -1;
            const bool act = (R0 <= rmax);

            // ---- phase A: layer1(t), parity 0 -> 1 ----
            if (act)
                layer(hsP, h1c, b1c, z, pos_emb, lds, ws1, wn1, mk0, mk1,
                      R0, rmax, tgate, tnew, lane, wv, tid, c, kbase, 0);
            asm volatile("s_waitcnt vmcnt(0)" ::: "memory");
            if (lane == 0) stf(prog8 + (b * 8 + wv) * 32, 2u * t);
            // tail-poll: deps of layer2(t)
            if (act) {
                const unsigned dataTh = 2u * t;
                const unsigned ringTh = (t > 3) ? (2u * (t - 2)) : 0u;
                const unsigned thA = (bA < b) ? dataTh : ringTh;
                const unsigned thB = (bB < b) ? dataTh : ringTh;
                if (thA) POLLW(prog8 + tid * 32, thA, sA)
                if (thB) POLLW(prog8 + (tid + 512) * 32, thB, sB)
                const int mlpTh = t - 3;
                const bool ownRow = (mlpTh > 0) && ((mlpTh >> 1) == b);
                if (tid < 64 && mlpTh > 0 && (tid == (b >> 1) || ownRow)) {
                    if (sM < mlpTh) {
                        int v;
                        for (;;) {
                            v = (int)ldf(mf + tid * 32);
                            if (v >= mlpTh) break;
                            __builtin_amdgcn_s_sleep(1);
                        }
                        sM = v;
                    }
                }
            }
            asm volatile("" ::: "memory");
            __syncthreads();

            // ---- phase B: layer2(t), parity 1 -> 0 ----
            if (act)
                layer(h1c, hsN, b2c, z, pos_emb, lds, ws2, wn2, mk0, mk1,
                      R0, rmax, tgate, -1, lane, wv, tid, c, kbase, 1);
            asm volatile("s_waitcnt vmcnt(0)" ::: "memory");
            if (lane == 0) stf(prog8 + (b * 8 + wv) * 32, 2u * t + 1u);
            // tail-poll: deps of layer1(t+1)
            if (t < 256 && R0 <= t + 1) {
                const unsigned dataTh = 2u * t + 1u;
                const unsigned ringTh = (t >= 2) ? (2u * (t - 1) + 1u) : 0u;
                const unsigned thA = (bA < b) ? dataTh : ringTh;
                const unsigned thB = (bB < b) ? dataTh : ringTh;
                if (thA) POLLW(prog8 + tid * 32, thA, sA)
                if (thB) POLLW(prog8 + (tid + 512) * 32, thB, sB)
            }
            asm volatile("" ::: "memory");
            __syncthreads();
        }

        // X_out from STH parity 0 (final Hs rows of this block)
        if (wv < 2) {
            const int r = R0 + wv;
            const float* strow = lds + STH_L + wv * HD;
            const int f = lane & 15, kp = lane >> 4;
            float sacc = 0.f;
#pragma unroll
            for (int k = 0; k < 32; ++k)
                sacc = fmaf(strow[kp * 32 + k], Wf[(kp * 32 + k) * 16 + f], sacc);
            sacc += __shfl_xor(sacc, 16);
            sacc += __shfl_xor(sacc, 32);
            if (lane < 16) out[NN * NN + r * 16 + f] = sacc + bf[f];
        }
    } else {
        // ---- MLP block: trails producers via SPARSE sub-flag waits ----
        const int mb = b - GNN_NB;
        const int ks = wv * 16;
        float4 wm[16];
#pragma unroll
        for (int kk = 0; kk < 16; ++kk)
            wm[kk] = *(const float4*)(Wm1 + (128 + ks + kk) * 256 + 4 * lane);
        {
            unsigned* tg = (unsigned*)(lds + TGT_L);
            for (int rr = 0; rr < 32; ++rr) {
                const int r = wv * 32 + rr;
#pragma unroll
                for (int q = 0; q < 4; ++q) {
                    const int j = q * 64 + lane;
                    const unsigned long long bm = __ballot(j < r && targets[r * NN + j] != 0);
                    if (lane == 0) {
                        tg[r * 8 + 2 * q]     = (unsigned)bm;
                        tg[r * 8 + 2 * q + 1] = (unsigned)(bm >> 32);
                    }
                }
            }
        }
        if (tid < 256) {
            lds[W2_L + tid] = Wm2[tid];
            float acc = bm1[tid];
            for (int k = 0; k < HD; ++k) acc = fmaf(z[k], Wm1[(256 + k) * 256 + tid], acc);
            lds[CZ_L + tid] = acc;
        }
        if (tid < 32) ((unsigned*)(lds + ANC_L))[tid] = 0u;
        if (tid == 0) lds[LP_L] = 0.f;
        __syncthreads();

        unsigned cA = 0, cB = 0;  // caches for the two fixed producer blocks
        for (int s = 1; s <= 255; ++s) {
            // Need Hs(s) rows {4mb..4mb+3} (blocks 2mb,2mb+1) + row s (block s>>1):
            // all 8 sub-flags of those blocks >= 2s+1. tid<24: 3 blocks x 8 waves.
            if (4 * mb < s && tid < 24) {
                const unsigned need = 2u * (unsigned)s + 1u;
                const int which = tid >> 3, wvf = tid & 7;
                if (which == 0) {
                    POLLW(prog8 + ((2 * mb) * 8 + wvf) * 32, need, cA)
                } else if (which == 1) {
                    POLLW(prog8 + ((2 * mb + 1) * 8 + wvf) * 32, need, cB)
                } else {
                    const unsigned* p = prog8 + ((s >> 1) * 8 + wvf) * 32;
                    unsigned v;
                    for (;;) { v = ldf(p); if (v >= need) break; __builtin_amdgcn_s_sleep(1); }
                }
            }
            __syncthreads();
            const float* hsP = ws + HS_OFF + (s % 3) * 32768;
            if (4 * mb < s) {
                ct_calc(hsP, pos_emb, Wm1, lds, s);
                __syncthreads();
                mlp_step(hsP, bm2, wm, lds, mb, s);
            }
            __syncthreads();  // all reads of Hs(s) done (vmcnt drained per wave)
            if (tid == 0) stf(mf + mb * 32, (unsigned)s);
        }
        __syncthreads();
        if (tid == 0) atomicAdd(lp_out, lds[LP_L]);
    }
}

extern "C" void kernel_launch(void* const* d_in, const int* in_sizes, int n_in,
                              void* d_out, int out_size, void* d_ws, size_t ws_size,
                              hipStream_t stream)
{
    const float* z       = (const float*)d_in[0];
    const int*   targets = (const int*)d_in[1];
    const float* pos_emb = (const float*)d_in[2];
    const float* Ws1     = (const float*)d_in[3];
    const float* Wn1     = (const float*)d_in[4];
    const float* b1      = (const float*)d_in[5];
    const float* Ws2     = (const float*)d_in[6];
    const float* Wn2     = (const float*)d_in[7];
    const float* b2      = (const float*)d_in[8];
    const float* Wm1     = (const float*)d_in[9];
    const float* bm1     = (const float*)d_in[10];
    const float* Wm2     = (const float*)d_in[11];
    const float* bm2     = (const float*)d_in[12];
    const float* Wf      = (const float*)d_in[13];
    const float* bf      = (const float*)d_in[14];
    float* out = (float*)d_out;
    float* ws  = (float*)d_ws;

    // zero prog8 + mf flag lines and the lp accumulator each call
    (void)hipMemsetAsync(ws + PROG8_OFF, 0, (128 * 8 + 64) * 32 * sizeof(unsigned), stream);
    (void)hipMemsetAsync(out + NN * NN + NN * 16, 0, sizeof(float), stream);

    void* args[17] = {
        (void*)&z, (void*)&targets, (void*)&pos_emb,
        (void*)&Ws1, (void*)&Wn1, (void*)&b1,
        (void*)&Ws2, (void*)&Wn2, (void*)&b2,
        (void*)&Wm1, (void*)&bm1, (void*)&Wm2, (void*)&bm2,
        (void*)&Wf, (void*)&bf, (void*)&out, (void*)&ws
    };
    (void)hipLaunchCooperativeKernel((const void*)fused_gnn, dim3(NBLK), dim3(NTHR),
                                     args, 0, stream);
}

// Round 16
// 1794.099 us; speedup vs baseline: 1.5341x; 1.2683x over previous
//
#include <hip/hip_runtime.h>

#define NN 256
#define HD 128
#define GNN_NB 128
#define MLP_NB 64
#define NBLK 192
#define NTHR 512
#define D_HS 4
#define D_H1 3

// ws float offsets (cross-block-mutable data accessed ONLY via sc1 atomics)
#define HS_OFF 0                    // ring: 4 x 32768 floats
#define H1R_OFF 131072              // ring: 3 x 32768 floats
#define PROG_OFF 229376             // 128 gnn progress lines, stride 32 u32
#define MF_OFF   233472             // 64 mlp progress lines, stride 32 u32

// GNN-block LDS (floats)
#define STH_L 0      // [2 parity][2 rows][128] own h rows
#define STM_L 512    // [2][128] combined m rows
#define PT_L  768    // [8][2][128] gather partials
// MLP-block LDS (floats)
#define TGT_L 0
#define PTM_L 2048
#define PT3_L 10240
#define HC_L  11264
#define CT_L  11776
#define CZ_L  12032
#define W2_L  12288
#define HP_L  12544
#define PART_L 12800
#define ANC_L 13312
#define LP_L  13344
#define LDS_FLOATS 13360

// ---- device-coherent access (relaxed agent atomics -> sc1, bypass L1/L2) ----
__device__ __forceinline__ float2 ldc_f2(const float* p) {
    unsigned long long u = __hip_atomic_load((const unsigned long long*)p,
                                             __ATOMIC_RELAXED, __HIP_MEMORY_SCOPE_AGENT);
    float2 r;
    r.x = __uint_as_float((unsigned)u);
    r.y = __uint_as_float((unsigned)(u >> 32));
    return r;
}
__device__ __forceinline__ void stc_f(float* p, float v) {
    __hip_atomic_store((unsigned*)p, __float_as_uint(v),
                       __ATOMIC_RELAXED, __HIP_MEMORY_SCOPE_AGENT);
}
__device__ __forceinline__ unsigned ldf(const unsigned* p) {
    return __hip_atomic_load(p, __ATOMIC_RELAXED, __HIP_MEMORY_SCOPE_AGENT);
}
__device__ __forceinline__ void stf(unsigned* p, unsigned v) {
    __hip_atomic_store(p, v, __ATOMIC_RELAXED, __HIP_MEMORY_SCOPE_AGENT);
}

// block barrier that does NOT drain vmcnt
__device__ __forceinline__ void bar_lds() {
    asm volatile("s_waitcnt lgkmcnt(0)\n\ts_barrier" ::: "memory");
}

#define POLLW(ptr, th, cache) \
    if ((cache) < (th)) { \
        unsigned v_; \
        for (;;) { v_ = ldf(ptr); if (v_ >= (th)) break; __builtin_amdgcn_s_sleep(1); } \
        (cache) = v_; \
    }

#define ISS(i) \
    float2 va##i, vb##i, vc##i, vd##i; \
    if ((i) < nst) { \
        const float* p_ = gsrc + (i) * 32 * HD; \
        if ((un >> (4 * (i)    )) & 1u) va##i = ldc_f2(p_); \
        if ((un >> (4 * (i) + 1)) & 1u) vb##i = ldc_f2(p_ + HD); \
        if ((un >> (4 * (i) + 2)) & 1u) vc##i = ldc_f2(p_ + 2 * HD); \
        if ((un >> (4 * (i) + 3)) & 1u) vd##i = ldc_f2(p_ + 3 * HD); \
    }
#define ACCP(v, b) { \
    const float f0_ = (float)((s0 >> (b)) & 1u); \
    const float f1_ = (float)((s1 >> (b)) & 1u); \
    m0.x = fmaf(f0_, v.x, m0.x); m0.y = fmaf(f0_, v.y, m0.y); \
    m1.x = fmaf(f1_, v.x, m1.x); m1.y = fmaf(f1_, v.y, m1.y); }
#define ACC1(v, b) if ((un >> (b)) & 1u) { ACCP(v, b) }
#define CNS(i) if ((i) < nst) { ACC1(va##i, 4*(i)) ACC1(vb##i, 4*(i)+1) \
                                ACC1(vc##i, 4*(i)+2) ACC1(vd##i, 4*(i)+3) }

// One GNN layer for rows {R0, R0+1}. h rows in STH[pr] (LDS), outputs -> STH[pr^1].
// Gather sc1 direct-to-register; matvec col-per-lane with shuffle k-reduce.
__device__ __forceinline__ void layer(const float* src, float* dst, float bc,
    const float* z, const float* pos_emb, float* lds,
    const float (&wsA)[32], const float (&wnA)[32],
    unsigned mk0, unsigned mk1,
    int R0, int rmax, int tgate, int tnew, int lane, int wv, int tid, int c, int kbase,
    int pr)
{
    const int rmaxblk = min(rmax, R0 + 1);
    const int nst = (rmaxblk + 31) >> 5;
    const unsigned s0 = (R0     < tgate) ? mk0 : 0u;
    const unsigned s1 = (R0 + 1 < tgate) ? mk1 : 0u;
    const unsigned un = s0 | s1;
    float* sthR = lds + STH_L + pr * 256;        // read buffer
    float* sthW = lds + STH_L + (pr ^ 1) * 256;  // write buffer

    // new node: h row := z + pos_emb[tnew] (into READ buffer, consumed this phase)
    if (tnew >= R0 && tnew < R0 + 2) {
        const int dr = tnew - R0;
        if (tid < HD) sthR[dr * HD + tid] = z[tid] + pos_emb[tnew * HD + tid];
    }

    // gather: wave wv owns src rows {32c' + 4wv + ss}; masked loads all in flight
    const float* gsrc = src + wv * 4 * HD + 2 * lane;
    float2 m0 = make_float2(0.f, 0.f), m1 = m0;
    ISS(0) ISS(1) ISS(2) ISS(3) ISS(4) ISS(5) ISS(6) ISS(7)
    CNS(0) CNS(1) CNS(2) CNS(3) CNS(4) CNS(5) CNS(6) CNS(7)

    // publish m partials
    float* pt = lds + PT_L + (wv * 2) * HD + 2 * lane;
    *(float2*)pt = m0;
    *(float2*)(pt + HD) = m1;
    bar_lds();
    // combine partials -> STM (2 rows x 128 k, threads 0..255)
    if (tid < 256) {
        const int dr = tid >> 7, k = tid & 127;
        float s = 0.f;
#pragma unroll
        for (int w = 0; w < 8; ++w) s += lds[PT_L + (w * 2 + dr) * HD + k];
        lds[STM_L + dr * HD + k] = s;
    }
    bar_lds();
    // matvec: lane accumulates its col over its 32-k slice, butterfly k-reduce
    float acc0 = 0.f, acc1 = 0.f;
#pragma unroll
    for (int q = 0; q < 8; ++q) {
        const float4 h0 = *(const float4*)(sthR + kbase + 4 * q);
        const float4 mm0 = *(const float4*)(lds + STM_L + kbase + 4 * q);
        const float4 h1 = *(const float4*)(sthR + HD + kbase + 4 * q);
        const float4 mm1 = *(const float4*)(lds + STM_L + HD + kbase + 4 * q);
        acc0 = fmaf(h0.x, wsA[4*q],   fmaf(mm0.x, wnA[4*q],   acc0));
        acc0 = fmaf(h0.y, wsA[4*q+1], fmaf(mm0.y, wnA[4*q+1], acc0));
        acc0 = fmaf(h0.z, wsA[4*q+2], fmaf(mm0.z, wnA[4*q+2], acc0));
        acc0 = fmaf(h0.w, wsA[4*q+3], fmaf(mm0.w, wnA[4*q+3], acc0));
        acc1 = fmaf(h1.x, wsA[4*q],   fmaf(mm1.x, wnA[4*q],   acc1));
        acc1 = fmaf(h1.y, wsA[4*q+1], fmaf(mm1.y, wnA[4*q+1], acc1));
        acc1 = fmaf(h1.z, wsA[4*q+2], fmaf(mm1.z, wnA[4*q+2], acc1));
        acc1 = fmaf(h1.w, wsA[4*q+3], fmaf(mm1.w, wnA[4*q+3], acc1));
    }
    acc0 += __shfl_xor(acc0, 16); acc0 += __shfl_xor(acc0, 32);
    acc1 += __shfl_xor(acc1, 16); acc1 += __shfl_xor(acc1, 32);
    const float o0 = fmaxf(acc0 + bc, 0.f);
    const float o1 = fmaxf(acc1 + bc, 0.f);
    // store + next-phase STH (parity write buffer: no cross-wave hazard)
    const int kg = lane >> 4;
    if (kg == 0) { if (R0     <= rmaxblk) stc_f(dst + R0 * HD + c, o0); }
    else if (kg == 1) { if (R0 + 1 <= rmaxblk) stc_f(dst + (R0 + 1) * HD + c, o1); }
    else if (kg == 2) sthW[c] = o0;
    else              sthW[HD + c] = o1;
}

// ---- MLP helpers (proven numerics) ----
__device__ __forceinline__ void ct_calc(const float* hsP, const float* pos_emb,
                                        const float* Wm1, float* lds, int s)
{
    const int tid = threadIdx.x;
    if (tid < 64) {
        const float2 v = ldc_f2(hsP + s * HD + 2 * tid);
        lds[HP_L + 2 * tid] = v.x; lds[HP_L + 2 * tid + 1] = v.y;
    } else if (tid < 128) {
        const int l2 = tid - 64;
        lds[HP_L + 128 + 2 * l2]     = pos_emb[s * HD + 2 * l2];
        lds[HP_L + 128 + 2 * l2 + 1] = pos_emb[s * HD + 2 * l2 + 1];
    }
    __syncthreads();
    const int c = tid & 255, half = tid >> 8;
    float acc = 0.f;
    const float* w = half ? (Wm1 + 384 * 256 + c) : (Wm1 + c);
    const float* hh = lds + HP_L + half * 128;
#pragma unroll 4
    for (int k = 0; k < HD; ++k) acc = fmaf(hh[k], w[k * 256], acc);
    lds[PART_L + half * 256 + c] = acc;
    __syncthreads();
    if (tid < 256)
        lds[CT_L + tid] = lds[CZ_L + tid] + lds[PART_L + tid] + lds[PART_L + 256 + tid];
}

__device__ __forceinline__ void mlp_step(const float* hsP, const float* bm2,
                                         const float4 (&wm)[16], float* lds, int mb, int s)
{
    const int tid = threadIdx.x, lane = tid & 63, wv = tid >> 6;
    const int ks = wv * 16;
    if (wv < 4) {
        const int i = 4 * mb + wv;
        float2 v = make_float2(0.f, 0.f);
        if (i < s) v = ldc_f2(hsP + i * HD + 2 * lane);
        *(float2*)(lds + HC_L + wv * HD + 2 * lane) = v;
    }
    __syncthreads();
    float4 a0 = make_float4(0.f, 0.f, 0.f, 0.f), a1 = a0, a2 = a0, a3 = a0;
#pragma unroll
    for (int kk = 0; kk < 16; ++kk) {
        const int k = ks + kk;
        const float h0 = lds[HC_L + 0 * HD + k];
        const float h1 = lds[HC_L + 1 * HD + k];
        const float h2 = lds[HC_L + 2 * HD + k];
        const float h3 = lds[HC_L + 3 * HD + k];
        const float4 w = wm[kk];
        a0.x = fmaf(h0, w.x, a0.x); a0.y = fmaf(h0, w.y, a0.y);
        a0.z = fmaf(h0, w.z, a0.z); a0.w = fmaf(h0, w.w, a0.w);
        a1.x = fmaf(h1, w.x, a1.x); a1.y = fmaf(h1, w.y, a1.y);
        a1.z = fmaf(h1, w.z, a1.z); a1.w = fmaf(h1, w.w, a1.w);
        a2.x = fmaf(h2, w.x, a2.x); a2.y = fmaf(h2, w.y, a2.y);
        a2.z = fmaf(h2, w.z, a2.z); a2.w = fmaf(h2, w.w, a2.w);
        a3.x = fmaf(h3, w.x, a3.x); a3.y = fmaf(h3, w.y, a3.y);
        a3.z = fmaf(h3, w.z, a3.z); a3.w = fmaf(h3, w.w, a3.w);
    }
    *(float4*)(lds + PTM_L + (wv * 4 + 0) * 256 + 4 * lane) = a0;
    *(float4*)(lds + PTM_L + (wv * 4 + 1) * 256 + 4 * lane) = a1;
    *(float4*)(lds + PTM_L + (wv * 4 + 2) * 256 + 4 * lane) = a2;
    *(float4*)(lds + PTM_L + (wv * 4 + 3) * 256 + 4 * lane) = a3;
    __syncthreads();
    {
        const int c = tid & 255, ci2 = (tid >> 8) * 2;
#pragma unroll
        for (int q = 0; q < 2; ++q) {
            const int ci = ci2 + q;
            float v = lds[CT_L + c];
#pragma unroll
            for (int w = 0; w < 8; ++w) v += lds[PTM_L + (w * 4 + ci) * 256 + c];
            lds[PT3_L + ci * 256 + c] = fmaxf(v, 0.f) * lds[W2_L + c];
        }
    }
    __syncthreads();
    if (wv < 4) {
        const int ci = wv, i = 4 * mb + ci;
        if (i < s) {
            float sd = lds[PT3_L + ci * 256 + lane] + lds[PT3_L + ci * 256 + 64 + lane]
                     + lds[PT3_L + ci * 256 + 128 + lane] + lds[PT3_L + ci * 256 + 192 + lane];
#pragma unroll
            for (int off = 32; off > 0; off >>= 1) sd += __shfl_xor(sd, off);
            if (lane == 0) {
                const unsigned* gtl = (const unsigned*)(lds + TGT_L) + s * 8;
                unsigned* ancl = (unsigned*)(lds + ANC_L);
                const float logit = sd + bm2[0];
                const float prob = 1.f / (1.f + expf(-logit));
                unsigned cnt = 0, has = 0;
#pragma unroll
                for (int w = 0; w < 8; ++w) {
                    const unsigned av = ancl[ci * 8 + w];
                    cnt += __popc(av);
                    has |= av & gtl[w];
                }
                const float supp = ldexpf(1.f, -(int)cnt);  // 0.5^cnt exact
                const float adj = prob * supp;
                const unsigned gt = (gtl[i >> 5] >> (i & 31)) & 1u;
                const float lpv = gt ? logf(adj + 1e-12f) : logf(1.f - adj + 1e-12f);
                atomicAdd((float*)(lds + LP_L), lpv);
                if (has | gt) ancl[ci * 8 + (s >> 5)] |= (1u << (s & 31));
            }
        }
    }
}

extern "C" __global__ void __launch_bounds__(NTHR)
fused_gnn(const float* z, const int* targets, const float* pos_emb,
          const float* Ws1, const float* Wn1, const float* b1,
          const float* Ws2, const float* Wn2, const float* b2,
          const float* Wm1, const float* bm1, const float* Wm2, const float* bm2,
          const float* Wf, const float* bf, float* out, float* ws)
{
    __shared__ __align__(16) float lds[LDS_FLOATS];
    const int b = blockIdx.x;
    const int tid = threadIdx.x, lane = tid & 63, wv = tid >> 6;

    unsigned* prog = (unsigned*)(ws + PROG_OFF);
    unsigned* mf   = (unsigned*)(ws + MF_OFF);
    float* lp_out = out + NN * NN + NN * 16;

    if (b < GNN_NB) {
        const int R0 = b * 2;
        const int c = 16 * wv + (lane & 15);
        const int kbase = 32 * (lane >> 4);
        float ws1[32], wn1[32], ws2[32], wn2[32];
#pragma unroll
        for (int i = 0; i < 32; ++i) {
            ws1[i] = Ws1[(kbase + i) * HD + c];
            wn1[i] = Wn1[(kbase + i) * HD + c];
            ws2[i] = Ws2[(kbase + i) * HD + c];
            wn2[i] = Wn2[(kbase + i) * HD + c];
        }
        const float b1c = b1[c], b2c = b2[c];
        unsigned mk0, mk1;
        {
            const int srcl = (lane < 32) ? (((lane >> 2) << 5) + wv * 4 + (lane & 3)) : 0;
#define BALLOT_MK(dr, dst) { \
            const int r_ = R0 + (dr); \
            const bool p_ = (lane < 32) && (srcl < r_) && (targets[r_ * NN + srcl] != 0); \
            const unsigned long long bm_ = __ballot(p_); \
            dst = (unsigned)__builtin_amdgcn_readfirstlane((int)(unsigned)bm_); }
            BALLOT_MK(0, mk0) BALLOT_MK(1, mk1)
#undef BALLOT_MK
        }
        // init: STH parity0, Hs(0) slot 0, tgt output
        if (tid < 256) lds[STH_L + tid] = (b == 0 && tid < HD) ? z[tid] : 0.f;
        if (tid < 256) {
            const int dr = tid >> 7, cc = tid & 127, r = R0 + dr;
            stc_f(ws + HS_OFF + r * HD + cc, (r == 0) ? z[cc] : 0.f);
        }
        if (wv < 2) {
            const int r = R0 + wv;
            const int4 tv = ((const int4*)(targets + r * NN))[lane];
            float4 ov;
            ov.x = (4 * lane     < r) ? (float)tv.x : 0.f;
            ov.y = (4 * lane + 1 < r) ? (float)tv.y : 0.f;
            ov.z = (4 * lane + 2 < r) ? (float)tv.z : 0.f;
            ov.w = (4 * lane + 3 < r) ? (float)tv.w : 0.f;
            ((float4*)(out + r * NN))[lane] = ov;
        }
        __syncthreads();  // drain init stores
        if (tid == 0) stf(prog + b * 32, 1u);

        unsigned seenP = 0;   // tid < GNN_NB: cached prog[tid]
        int      seenM = 0;   // tid in [GNN_NB, GNN_NB+MLP_NB): cached mf[tid-GNN_NB]

        for (int t = 1; t <= 256; ++t) {
            const float* hsP = ws + HS_OFF + ((t - 1) % D_HS) * 32768;
            float* h1c = ws + H1R_OFF + (t % D_H1) * 32768;
            float* hsN = ws + HS_OFF + (t % D_HS) * 32768;
            const int rmax  = (t <= 255) ? t : 255;
            const int tgate = (t <= 255) ? t : 300;
            const int tnew  = (t <= 255) ? t : -1;
            const bool act = (R0 <= rmax);

            // layer1(t): data b'<b >= 2t-1; H1 ring (slot t%3, occupant t-3):
            // readers layer2(t-3) done <=> all prog >= 2(t-3)+1
            if (act) {
                {
                    const unsigned dataTh = 2u * t - 1u;
                    const unsigned ringTh = (t > D_H1) ? (2u * (t - D_H1) + 1u) : 0u;
                    if (tid < GNN_NB) {
                        const unsigned th = (tid < b) ? dataTh : ringTh;
                        if (seenP < th) {
                            unsigned v;
                            for (;;) {
                                v = ldf(prog + tid * 32);
                                if (v >= th) break;
                                __builtin_amdgcn_s_sleep(1);
                            }
                            seenP = v;
                        }
                    }
                    __syncthreads();
                    asm volatile("" ::: "memory");
                }
                layer(hsP, h1c, b1c, z, pos_emb, lds, ws1, wn1,
                      mk0, mk1, R0, rmax, tgate, tnew, lane, wv, tid, c, kbase, 0);
            }
            __syncthreads();
            if (tid == 0) stf(prog + b * 32, 2u * t);

            // layer2(t): data b'<b >= 2t; Hs ring (slot t%4, occupant t-4, rows 2b,2b+1):
            // gnn readers: layer1(t-3) done <=> prog >= 2(t-3); MLP readers sparse.
            if (act) {
                {
                    const unsigned dataTh = 2u * t;
                    const unsigned ringTh = (t > D_HS) ? (2u * (t - D_HS + 1)) : 0u;
                    const int mlpTh = t - D_HS;
                    const bool ownRow = (mlpTh > 0) && ((mlpTh >> 1) == b);
                    if (tid < GNN_NB) {
                        const unsigned th = (tid < b) ? dataTh : ringTh;
                        if (seenP < th) {
                            unsigned v;
                            for (;;) {
                                v = ldf(prog + tid * 32);
                                if (v >= th) break;
                                __builtin_amdgcn_s_sleep(1);
                            }
                            seenP = v;
                        }
                    } else if (tid < GNN_NB + MLP_NB) {
                        const int mi = tid - GNN_NB;
                        const int thm = (mlpTh > 0 && (mi == (b >> 1) || ownRow)) ? mlpTh : 0;
                        if (thm > 0 && seenM < thm) {
                            int v;
                            for (;;) {
                                v = (int)ldf(mf + mi * 32);
                                if (v >= thm) break;
                                __builtin_amdgcn_s_sleep(1);
                            }
                            seenM = v;
                        }
                    }
                    __syncthreads();
                    asm volatile("" ::: "memory");
                }
                layer(h1c, hsN, b2c, z, pos_emb, lds, ws2, wn2,
                      mk0, mk1, R0, rmax, tgate, -1, lane, wv, tid, c, kbase, 1);
            }
            __syncthreads();
            if (tid == 0) stf(prog + b * 32, 2u * t + 1u);
        }

        // X_out from STH parity 0 (final Hs rows of this block)
        if (wv < 2) {
            const int r = R0 + wv;
            const float* strow = lds + STH_L + wv * HD;
            const int f = lane & 15, kp = lane >> 4;
            float sacc = 0.f;
#pragma unroll
            for (int k = 0; k < 32; ++k)
                sacc = fmaf(strow[kp * 32 + k], Wf[(kp * 32 + k) * 16 + f], sacc);
            sacc += __shfl_xor(sacc, 16);
            sacc += __shfl_xor(sacc, 32);
            if (lane < 16) out[NN * NN + r * 16 + f] = sacc + bf[f];
        }
    } else {
        // ---- MLP block: trails producers via SPARSE prog waits ----
        const int mb = b - GNN_NB;
        const int ks = wv * 16;
        float4 wm[16];
#pragma unroll
        for (int kk = 0; kk < 16; ++kk)
            wm[kk] = *(const float4*)(Wm1 + (128 + ks + kk) * 256 + 4 * lane);
        {
            unsigned* tg = (unsigned*)(lds + TGT_L);
            for (int rr = 0; rr < 32; ++rr) {
                const int r = wv * 32 + rr;
#pragma unroll
                for (int q = 0; q < 4; ++q) {
                    const int j = q * 64 + lane;
                    const unsigned long long bm = __ballot(j < r && targets[r * NN + j] != 0);
                    if (lane == 0) {
                        tg[r * 8 + 2 * q]     = (unsigned)bm;
                        tg[r * 8 + 2 * q + 1] = (unsigned)(bm >> 32);
                    }
                }
            }
        }
        if (tid < 256) {
            lds[W2_L + tid] = Wm2[tid];
            float acc = bm1[tid];
            for (int k = 0; k < HD; ++k) acc = fmaf(z[k], Wm1[(256 + k) * 256 + tid], acc);
            lds[CZ_L + tid] = acc;
        }
        if (tid < 32) ((unsigned*)(lds + ANC_L))[tid] = 0u;
        if (tid == 0) lds[LP_L] = 0.f;

        unsigned seenP = 0;  // tid < GNN_NB: cached prog[tid]
        for (int s = 1; s <= 255; ++s) {
            // Need Hs(s) rows {4mb..4mb+3} (blocks 2mb,2mb+1) and row s (block s>>1):
            // only those 3 flags >= 2s+1; skip entirely if no candidates yet.
            if (4 * mb < s && tid < GNN_NB) {
                const bool needed = (tid == 2 * mb) || (tid == 2 * mb + 1) ||
                                    (tid == (s >> 1));
                if (needed) {
                    const unsigned need = 2u * (unsigned)s + 1u;
                    if (seenP < need) {
                        unsigned v;
                        for (;;) {
                            v = ldf(prog + tid * 32);
                            if (v >= need) break;
                            __builtin_amdgcn_s_sleep(1);
                        }
                        seenP = v;
                    }
                }
            }
            __syncthreads();
            const float* hsP = ws + HS_OFF + (s % D_HS) * 32768;
            if (4 * mb < s) {
                ct_calc(hsP, pos_emb, Wm1, lds, s);
                __syncthreads();
                mlp_step(hsP, bm2, wm, lds, mb, s);
            }
            __syncthreads();  // all reads of Hs(s) done (vmcnt drained per wave)
            if (tid == 0) stf(mf + mb * 32, (unsigned)s);
        }
        __syncthreads();
        if (tid == 0) atomicAdd(lp_out, lds[LP_L]);
    }
}

extern "C" void kernel_launch(void* const* d_in, const int* in_sizes, int n_in,
                              void* d_out, int out_size, void* d_ws, size_t ws_size,
                              hipStream_t stream)
{
    const float* z       = (const float*)d_in[0];
    const int*   targets = (const int*)d_in[1];
    const float* pos_emb = (const float*)d_in[2];
    const float* Ws1     = (const float*)d_in[3];
    const float* Wn1     = (const float*)d_in[4];
    const float* b1      = (const float*)d_in[5];
    const float* Ws2     = (const float*)d_in[6];
    const float* Wn2     = (const float*)d_in[7];
    const float* b2      = (const float*)d_in[8];
    const float* Wm1     = (const float*)d_in[9];
    const float* bm1     = (const float*)d_in[10];
    const float* Wm2     = (const float*)d_in[11];
    const float* bm2     = (const float*)d_in[12];
    const float* Wf      = (const float*)d_in[13];
    const float* bf      = (const float*)d_in[14];
    float* out = (float*)d_out;
    float* ws  = (float*)d_ws;

    // zero prog + mf flag lines and the lp accumulator each call
    (void)hipMemsetAsync(ws + PROG_OFF, 0, (GNN_NB + MLP_NB) * 32 * sizeof(unsigned), stream);
    (void)hipMemsetAsync(out + NN * NN + NN * 16, 0, sizeof(float), stream);

    void* args[17] = {
        (void*)&z, (void*)&targets, (void*)&pos_emb,
        (void*)&Ws1, (void*)&Wn1, (void*)&b1,
        (void*)&Ws2, (void*)&Wn2, (void*)&b2,
        (void*)&Wm1, (void*)&bm1, (void*)&Wm2, (void*)&bm2,
        (void*)&Wf, (void*)&bf, (void*)&out, (void*)&ws
    };
    (void)hipLaunchCooperativeKernel((const void*)fused_gnn, dim3(NBLK), dim3(NTHR),
                                     args, 0, stream);
}